// Round 1
// baseline (638.651 us; speedup 1.0000x reference)
//
#include <hip/hip_runtime.h>
#include <hip/hip_bf16.h>

namespace {
constexpr int Md = 4096, Kd = 4096, Nd = 12288;
constexpr int BM = 128, BN = 128, BK = 64;
constexpr int TK = Kd / BK;

typedef __attribute__((ext_vector_type(4))) float f4;
typedef __attribute__((ext_vector_type(8))) short b8;

__device__ __forceinline__ unsigned short f2bf(float f) {
  unsigned u = __float_as_uint(f);
  u += 0x7FFFu + ((u >> 16) & 1u);
  return (unsigned short)(u >> 16);
}

__global__ __launch_bounds__(256, 2)
void qgemm_kernel(const float* __restrict__ X, const int* __restrict__ QW,
                  const int* __restrict__ QZ, const float* __restrict__ SC,
                  const float* __restrict__ BS, float* __restrict__ OUT)
{
  // LDS: As[r][kb] / Bs[n][kb] with 16B-block XOR swizzle (kb ^ (row&7))
  __shared__ alignas(16) unsigned short As[BM * BK];
  __shared__ alignas(16) unsigned short Bs[BN * BK];

  // XCD-aware bijective swizzle (grid = 3072, divisible by 8)
  const int nwg = gridDim.x;
  const int cpx = nwg >> 3;
  const int b = blockIdx.x;
  const int swz = (b & 7) * cpx + (b >> 3);
  const int bm = swz / (Nd / BN);
  const int bn = swz % (Nd / BN);
  const int m0 = bm * BM, n0 = bn * BN;

  const int tid = threadIdx.x;
  const int lane = tid & 63;
  const int wid = tid >> 6;
  const int wr = wid >> 1, wc = wid & 1;   // 2x2 waves, each 64x64 output

  // A staging map: thread -> (row ar+i*32, k-block akb), coalesced 8-fp32 chunks
  const int ar = tid >> 3;     // 0..31
  const int akb = tid & 7;     // 0..7
  // B staging map: thread -> fixed n, 4 consecutive k8 rows (coalesced per row)
  const int bnl = tid & 127;          // 0..127
  const int bk8 = (tid >> 7) << 2;    // 0 or 4

  f4 acc[4][4];
  #pragma unroll
  for (int i = 0; i < 4; ++i)
    #pragma unroll
    for (int j = 0; j < 4; ++j) acc[i][j] = {0.0f, 0.0f, 0.0f, 0.0f};

  f4 a0[4], a1[4]; int bw[4]; float sS, sC;
  f4 na0[4], na1[4]; int nbw[4]; float nS, nC;

  auto loadT = [&](int t, f4* x0, f4* x1, int* w, float& s, float& c) {
    const float* xp = X + (size_t)(m0 + ar) * Kd + t * BK + akb * 8;
    #pragma unroll
    for (int i = 0; i < 4; ++i) {
      const f4* p = (const f4*)(xp + (size_t)i * 32 * Kd);
      x0[i] = p[0];
      x1[i] = p[1];
    }
    const int* qp = QW + (size_t)(t * 8 + bk8) * Nd + n0 + bnl;
    #pragma unroll
    for (int i = 0; i < 4; ++i) w[i] = qp[(size_t)i * Nd];
    const int g = t >> 1;                       // BK=64 -> group constant per tile
    s = SC[(size_t)g * Nd + n0 + bnl];
    const int nab = n0 + bnl;
    const int z32 = QZ[(size_t)g * (Nd / 8) + (nab >> 3)];
    const int z = (z32 >> ((nab & 7) * 4)) & 15;
    c = (float)(z + 1) * s;                      // w = q*s - c
  };

  auto writeT = [&](const f4* x0, const f4* x1, const int* w, float s, float c) {
    #pragma unroll
    for (int i = 0; i < 4; ++i) {
      const int r = ar + i * 32;
      b8 v;
      v[0] = (short)f2bf(x0[i][0]); v[1] = (short)f2bf(x0[i][1]);
      v[2] = (short)f2bf(x0[i][2]); v[3] = (short)f2bf(x0[i][3]);
      v[4] = (short)f2bf(x1[i][0]); v[5] = (short)f2bf(x1[i][1]);
      v[6] = (short)f2bf(x1[i][2]); v[7] = (short)f2bf(x1[i][3]);
      *(b8*)&As[r * BK + ((akb ^ (r & 7)) << 3)] = v;
    }
    #pragma unroll
    for (int i = 0; i < 4; ++i) {
      const unsigned q = (unsigned)w[i];
      const int k8 = bk8 + i;
      b8 v;
      #pragma unroll
      for (int j = 0; j < 8; ++j) {
        const float qf = (float)((q >> (4 * j)) & 15u);
        v[j] = (short)f2bf(__builtin_fmaf(qf, s, -c));
      }
      *(b8*)&Bs[bnl * BK + ((k8 ^ (bnl & 7)) << 3)] = v;
    }
  };

  loadT(0, a0, a1, bw, sS, sC);
  writeT(a0, a1, bw, sS, sC);
  __syncthreads();

  for (int t = 0; t < TK; ++t) {
    if (t + 1 < TK) loadT(t + 1, na0, na1, nbw, nS, nC);  // issue early, hide under MFMA
    #pragma unroll
    for (int ks = 0; ks < 2; ++ks) {
      b8 af[4], bf[4];
      const int kb = ks * 4 + (lane >> 4);
      #pragma unroll
      for (int mi = 0; mi < 4; ++mi) {
        const int r = wr * 64 + mi * 16 + (lane & 15);
        af[mi] = *(const b8*)&As[r * BK + ((kb ^ (r & 7)) << 3)];
      }
      #pragma unroll
      for (int ni = 0; ni < 4; ++ni) {
        const int cc = wc * 64 + ni * 16 + (lane & 15);
        bf[ni] = *(const b8*)&Bs[cc * BK + ((kb ^ (cc & 7)) << 3)];
      }
      #pragma unroll
      for (int mi = 0; mi < 4; ++mi)
        #pragma unroll
        for (int ni = 0; ni < 4; ++ni)
          acc[mi][ni] = __builtin_amdgcn_mfma_f32_16x16x32_bf16(af[mi], bf[ni], acc[mi][ni], 0, 0, 0);
    }
    if (t + 1 < TK) {
      __syncthreads();                 // all LDS reads of tile t done
      writeT(na0, na1, nbw, nS, nC);   // dequant + stage tile t+1
      __syncthreads();                 // writes visible
    }
  }

  // Epilogue: C/D layout col = lane&15, row = (lane>>4)*4 + j  (m89/m91 verified)
  #pragma unroll
  for (int ni = 0; ni < 4; ++ni) {
    const int gn = n0 + wc * 64 + ni * 16 + (lane & 15);
    const float bv = BS[gn];
    #pragma unroll
    for (int mi = 0; mi < 4; ++mi) {
      const int gm = m0 + wr * 64 + mi * 16 + ((lane >> 4) << 2);
      #pragma unroll
      for (int j = 0; j < 4; ++j)
        OUT[(size_t)(gm + j) * Nd + gn] = acc[mi][ni][j] + bv;
    }
  }
}
} // namespace

extern "C" void kernel_launch(void* const* d_in, const int* in_sizes, int n_in,
                              void* d_out, int out_size, void* d_ws, size_t ws_size,
                              hipStream_t stream) {
  const float* x  = (const float*)d_in[0];
  const int*   qw = (const int*)d_in[1];
  const int*   qz = (const int*)d_in[2];
  const float* sc = (const float*)d_in[3];
  const float* bs = (const float*)d_in[4];
  float* out = (float*)d_out;
  dim3 grid((Md / BM) * (Nd / BN));   // 32 * 96 = 3072
  qgemm_kernel<<<grid, dim3(256), 0, stream>>>(x, qw, qz, sc, bs, out);
}

// Round 3
// 411.180 us; speedup vs baseline: 1.5532x; 1.5532x over previous
//
#include <hip/hip_runtime.h>
#include <hip/hip_bf16.h>

namespace {
constexpr int Md = 4096, Kd = 4096, Nd = 12288;
constexpr int BM = 256, BN = 128, BK = 64;
constexpr int TK = Kd / BK;
constexpr int THREADS = 512;
constexpr size_t A_BYTES = (size_t)Md * Kd * 2;   // bf16 copy of X in d_ws
constexpr int LDS_BYTES = (2 * BM * BK + BN * BK) * 2;  // 81920

typedef __attribute__((ext_vector_type(4))) float f4;
typedef __attribute__((ext_vector_type(8))) short b8;

__device__ __forceinline__ unsigned cvtpk(float lo, float hi) {
  unsigned r;
  asm("v_cvt_pk_bf16_f32 %0, %1, %2" : "=v"(r) : "v"(lo), "v"(hi));
  return r;
}

__global__ __launch_bounds__(256)
void cvtA_kernel(const float* __restrict__ X, unsigned short* __restrict__ Xb, int n8) {
  int i = blockIdx.x * blockDim.x + threadIdx.x;
  const int stride = gridDim.x * blockDim.x;
  for (; i < n8; i += stride) {
    const f4* p = (const f4*)X + (size_t)i * 2;
    f4 a = p[0], b = p[1];
    uint4 o;
    o.x = cvtpk(a[0], a[1]); o.y = cvtpk(a[2], a[3]);
    o.z = cvtpk(b[0], b[1]); o.w = cvtpk(b[2], b[3]);
    ((uint4*)Xb)[i] = o;
  }
}

template<bool AWS>
__global__ __launch_bounds__(THREADS, 4)
void qgemm2(const float* __restrict__ X, const unsigned short* __restrict__ Xb,
            const int* __restrict__ QW, const int* __restrict__ QZ,
            const float* __restrict__ SC, const float* __restrict__ BS,
            float* __restrict__ OUT)
{
  extern __shared__ char smem[];
  unsigned short* As = (unsigned short*)smem;                       // [2][BM*BK]
  unsigned short* Bs = (unsigned short*)(smem + 2 * BM * BK * 2);   // [BN*BK]

  const int nwg = gridDim.x;
  const int cpx = nwg >> 3;
  const int b = blockIdx.x;
  const int swz = (b & 7) * cpx + (b >> 3);       // grid 1536 % 8 == 0 -> bijective
  const int bm = swz / (Nd / BN), bn = swz % (Nd / BN);
  const int m0 = bm * BM, n0 = bn * BN;

  const int tid = threadIdx.x, lane = tid & 63;
  const int wid = tid >> 6;
  const int wr = wid >> 1, wc = wid & 1;          // 4x2 waves, each 64x64 output

  const int n_l = tid & 127;                      // B staging: n within tile
  const int k8b = (tid >> 7) * 2;                 // B staging: first of 2 k8-rows

  f4 acc[4][4];
  #pragma unroll
  for (int i = 0; i < 4; ++i)
    #pragma unroll
    for (int j = 0; j < 4; ++j) acc[i][j] = {0.0f, 0.0f, 0.0f, 0.0f};

  // --- A staging: LDS linear dest, pre-swizzled global source (kb ^ (r&7)) ---
  auto stageA = [&](int t, int buf) {
    #pragma unroll
    for (int i = 0; i < 4; ++i) {
      const int c = i * THREADS + tid;            // 16B chunk index, 0..2047
      const int r = c >> 3, kbl = c & 7;
      const unsigned short* src = Xb + (size_t)(m0 + r) * Kd + t * BK + ((kbl ^ (r & 7)) << 3);
      __builtin_amdgcn_global_load_lds(
          (const __attribute__((address_space(1))) unsigned*)src,
          (__attribute__((address_space(3))) unsigned*)(As + buf * BM * BK + c * 8),
          16, 0, 0);
    }
  };
  auto stageA_f = [&](int t, int buf) {           // fallback: fp32 load + cvt inline
    #pragma unroll
    for (int i = 0; i < 4; ++i) {
      const int c = i * THREADS + tid;
      const int r = c >> 3, kbl = c & 7;
      const f4* src = (const f4*)(X + (size_t)(m0 + r) * Kd + t * BK + ((kbl ^ (r & 7)) << 3));
      f4 a = src[0], bb = src[1];
      uint4 o;
      o.x = cvtpk(a[0], a[1]); o.y = cvtpk(a[2], a[3]);
      o.z = cvtpk(bb[0], bb[1]); o.w = cvtpk(bb[2], bb[3]);
      *(uint4*)(As + buf * BM * BK + c * 8) = o;
    }
  };

  // --- B: load packed words + scale/zero to regs; dequant+write later ---
  auto loadB = [&](int t, int* w, float& s, float& negc) {
    const int* qp = QW + (size_t)(t * 8 + k8b) * Nd + n0 + n_l;
    w[0] = qp[0];
    w[1] = qp[Nd];
    const int g = t >> 1;                         // BK=64: group constant per tile
    s = SC[(size_t)g * Nd + n0 + n_l];
    const int nab = n0 + n_l;
    const int z32 = QZ[(size_t)g * (Nd / 8) + (nab >> 3)];
    const int z = (z32 >> ((nab & 7) * 4)) & 15;
    negc = -(float)(z + 1) * s;                   // w = fma(q, s, negc)
  };
  auto writeB = [&](const int* w, float s, float negc) {
    #pragma unroll
    for (int i = 0; i < 2; ++i) {
      const unsigned q = (unsigned)w[i];
      const int k8 = k8b + i;
      float f[8];
      #pragma unroll
      for (int j = 0; j < 8; ++j)
        f[j] = __builtin_fmaf((float)((q >> (4 * j)) & 15u), s, negc);
      uint4 o;
      o.x = cvtpk(f[0], f[1]); o.y = cvtpk(f[2], f[3]);
      o.z = cvtpk(f[4], f[5]); o.w = cvtpk(f[6], f[7]);
      const int chunk = (k8 ^ (n_l & 7)) << 3;    // 8 shorts per 16B chunk
      *(uint4*)(Bs + n_l * BK + chunk) = o;
    }
  };

  int bw[2]; float sS, sNC;
  int nbw[2]; float nS, nNC;

  // prologue: tile 0
  if constexpr (AWS) stageA(0, 0); else stageA_f(0, 0);
  loadB(0, bw, sS, sNC);
  writeB(bw, sS, sNC);
  __syncthreads();                                 // drains A0 DMA + B writes

  for (int t = 0; t < TK; ++t) {
    const int cb = t & 1;
    if (t + 1 < TK) {
      if constexpr (AWS) stageA(t + 1, cb ^ 1);    // DMA into other buffer, in flight across MFMA
      loadB(t + 1, nbw, nS, nNC);
    }
    #pragma unroll
    for (int ks = 0; ks < 2; ++ks) {
      b8 af[4], bf[4];
      const int kb = ks * 4 + (lane >> 4);
      #pragma unroll
      for (int mi = 0; mi < 4; ++mi) {
        const int r = wr * 64 + mi * 16 + (lane & 15);
        af[mi] = *(const b8*)&As[cb * BM * BK + r * BK + ((kb ^ (r & 7)) << 3)];
      }
      #pragma unroll
      for (int ni = 0; ni < 4; ++ni) {
        const int cc = wc * 64 + ni * 16 + (lane & 15);
        bf[ni] = *(const b8*)&Bs[cc * BK + ((kb ^ (cc & 7)) << 3)];
      }
      #pragma unroll
      for (int mi = 0; mi < 4; ++mi)
        #pragma unroll
        for (int ni = 0; ni < 4; ++ni)
          acc[mi][ni] = __builtin_amdgcn_mfma_f32_16x16x32_bf16(af[mi], bf[ni], acc[mi][ni], 0, 0, 0);
    }
    __syncthreads();                               // Bs reads done; A DMA drained
    if (t + 1 < TK) {
      if constexpr (!AWS) stageA_f(t + 1, cb ^ 1);
      writeB(nbw, nS, nNC);                        // dequant tile t+1 into Bs
    }
    __syncthreads();                               // Bs + A writes visible
  }

  // epilogue: C/D layout col = lane&15, row = (lane>>4)*4 + j
  #pragma unroll
  for (int ni = 0; ni < 4; ++ni) {
    const int gn = n0 + wc * 64 + ni * 16 + (lane & 15);
    const float bv = BS[gn];
    #pragma unroll
    for (int mi = 0; mi < 4; ++mi) {
      const int gm = m0 + wr * 64 + mi * 16 + ((lane >> 4) << 2);
      #pragma unroll
      for (int j = 0; j < 4; ++j)
        OUT[(size_t)(gm + j) * Nd + gn] = acc[mi][ni][j] + bv;
    }
  }
}
} // namespace

extern "C" void kernel_launch(void* const* d_in, const int* in_sizes, int n_in,
                              void* d_out, int out_size, void* d_ws, size_t ws_size,
                              hipStream_t stream) {
  const float* x  = (const float*)d_in[0];
  const int*   qw = (const int*)d_in[1];
  const int*   qz = (const int*)d_in[2];
  const float* sc = (const float*)d_in[3];
  const float* bs = (const float*)d_in[4];
  float* out = (float*)d_out;

  (void)hipFuncSetAttribute((const void*)qgemm2<true>,
                            hipFuncAttributeMaxDynamicSharedMemorySize, LDS_BYTES);
  (void)hipFuncSetAttribute((const void*)qgemm2<false>,
                            hipFuncAttributeMaxDynamicSharedMemorySize, LDS_BYTES);

  dim3 grid((Md / BM) * (Nd / BN));   // 16 * 96 = 1536
  if (ws_size >= A_BYTES) {
    unsigned short* xb = (unsigned short*)d_ws;
    const int n8 = Md * Kd / 8;
    cvtA_kernel<<<2048, 256, 0, stream>>>(x, xb, n8);
    qgemm2<true><<<grid, dim3(THREADS), LDS_BYTES, stream>>>(x, xb, qw, qz, sc, bs, out);
  } else {
    qgemm2<false><<<grid, dim3(THREADS), LDS_BYTES, stream>>>(x, nullptr, qw, qz, sc, bs, out);
  }
}